// Round 12
// baseline (121.439 us; speedup 1.0000x reference)
//
#include <hip/hip_runtime.h>

#define B_ROWS   262144
#define C_DIM    128
#define K_CLS    128
#define PAD_R    2048
#define PAD2     4096
#define QSPLIT   4
#define QROWS    (PAD_R / QSPLIT)
#define FSPLIT   4
#define TROWS    64
#define LSTRIDE  132            // u32 stride per pair-row (pad 128+4: read banks 2-way)
#define EPS_F    1e-8f
#define CHUNK    1024
#define G_CHUNKS 256

typedef float f32x4  __attribute__((ext_vector_type(4)));
typedef short bf16x8 __attribute__((ext_vector_type(8)));

__device__ __forceinline__ unsigned f2bf(float f) {
  unsigned u = __float_as_uint(f);
  return (u + 0x7fffu + ((u >> 16) & 1u)) >> 16;   // RNE bf16
}
__device__ __forceinline__ unsigned packbf(float a, float b) {
  return f2bf(a) | (f2bf(b) << 16);
}
__device__ __forceinline__ float bflo(unsigned u) { return __uint_as_float(u << 16); }
__device__ __forceinline__ float bfhi(unsigned u) { return __uint_as_float(u & 0xffff0000u); }

// lgkm-only barrier: LDS visibility without draining global-load vmcnt (T3/T4)
#define TILE_BARRIER()                                      \
  do {                                                      \
    asm volatile("s_waitcnt lgkmcnt(0)" ::: "memory");      \
    __builtin_amdgcn_s_barrier();                           \
  } while (0)

// ---------------- histogram over 1024-row chunks (+ numden zero) ----------------
__global__ __launch_bounds__(256) void hist_kernel(const int* __restrict__ y,
                                                   int* __restrict__ hist,
                                                   float* __restrict__ numden) {
  __shared__ int h[K_CLS];
  int g = blockIdx.x, tid = threadIdx.x;
  if (g == 0 && tid < 64) numden[tid] = 0.f;
  if (tid < K_CLS) h[tid] = 0;
  __syncthreads();
  for (int j = tid; j < CHUNK; j += 256) atomicAdd(&h[y[g * CHUNK + j]], 1);
  __syncthreads();
  if (tid < K_CLS) hist[g * K_CLS + tid] = h[tid];
}

// ---------------- per-class exclusive scan over chunks ----------------
__global__ __launch_bounds__(256) void scan_kernel(int* __restrict__ hist,
                                                   int* __restrict__ counts) {
  __shared__ int s[G_CHUNKS];
  int k = blockIdx.x, g = threadIdx.x;
  int v = hist[g * K_CLS + k];
  s[g] = v;
  __syncthreads();
  for (int off = 1; off < G_CHUNKS; off <<= 1) {
    int t = (g >= off) ? s[g - off] : 0;
    __syncthreads();
    s[g] += t;
    __syncthreads();
  }
  hist[g * K_CLS + k] = s[g] - v;          // exclusive prefix
  if (g == G_CHUNKS - 1) counts[k] = s[g]; // total count
}

// ---------------- stable ranks + scatter rows to class-sorted bf16 copy ----------------
// xg layout: [k][R][c] bf16 row-major; row = 64 u32 (256B). Coalesced x reads
// (own chunk), 256B-granule scattered writes. No ord array, no atomics.
__global__ __launch_bounds__(1024) void scatter_kernel(const float* __restrict__ x,
                                                       const int* __restrict__ y,
                                                       const int* __restrict__ hist,
                                                       unsigned int* __restrict__ xg) {
  __shared__ int yl[CHUNK];                        // 4KB
  __shared__ unsigned short R_l[CHUNK];            // 2KB
  __shared__ unsigned short cnt_sub[16][K_CLS];    // 4KB
  __shared__ int offs[K_CLS];
  const int g = blockIdx.x, tid = threadIdx.x;
  const int lane = tid & 63, w = tid >> 6;         // 16 waves = 16 subchunks
  if (tid < K_CLS) offs[tid] = hist[g * K_CLS + tid];
  {
    unsigned int* cz = (unsigned int*)cnt_sub;
    for (int i = tid; i < 16 * K_CLS / 2; i += 1024) cz[i] = 0;
  }
  __syncthreads();

  const int yy = y[g * CHUNK + w * 64 + lane];
  yl[w * 64 + lane] = yy;
  unsigned long long m = ~0ULL;
  #pragma unroll
  for (int b = 0; b < 7; ++b) {
    unsigned long long bb = __ballot((yy >> b) & 1);
    m &= ((yy >> b) & 1) ? bb : ~bb;
  }
  const int rig = (int)__popcll(m & ((1ULL << lane) - 1ULL));
  const int leader = __ffsll((long long)m) - 1;
  if (lane == leader) cnt_sub[w][yy] = (unsigned short)__popcll(m);
  __syncthreads();

  if (tid < K_CLS) {                       // exclusive prefix over 16 subchunks, per class
    int run = 0;
    #pragma unroll
    for (int s = 0; s < 16; ++s) {
      int t = cnt_sub[s][tid];
      cnt_sub[s][tid] = (unsigned short)run;
      run += t;
    }
  }
  __syncthreads();
  R_l[w * 64 + lane] = (unsigned short)(offs[yy] + (int)cnt_sub[w][yy] + rig);
  __syncthreads();

  // row-write phase: 16 threads/row, 64 rows per pass
  const int sub = tid & 15, jr = tid >> 4;
  for (int base = 0; base < CHUNK; base += 64) {
    const int j = base + jr;
    const int k = yl[j];
    const int R = (int)R_l[j];
    const float* src = x + (size_t)(g * CHUNK + j) * C_DIM + sub * 8;
    f32x4 a = *(const f32x4*)(src);
    f32x4 b = *(const f32x4*)(src + 4);
    uint4 pk;
    pk.x = packbf(a[0], a[1]);
    pk.y = packbf(a[2], a[3]);
    pk.z = packbf(b[0], b[1]);
    pk.w = packbf(b[2], b[3]);
    if (R < PAD2)
      *(uint4*)(&xg[((size_t)k * PAD2 + R) * 64 + sub * 4]) = pk;
  }
}

// ---------------- per-class X^T X via MFMA, streaming bf16, 4 blocks/class ----------------
// LDS: [pair u 0..31][c 0..127] u32 (pair u = tile rows 2u,2u+1 packed bf16), stride 132.
//   write: b128 contiguous per half-wave (0-conflict); read: 2 lanes/bank (free)
__global__ __launch_bounds__(512, 4) void gemm_kernel(const unsigned int* __restrict__ xg,
                                                      const int* __restrict__ counts,
                                                      float* __restrict__ spart,
                                                      float* __restrict__ sums_part,
                                                      float* __restrict__ sqs_part,
                                                      float* __restrict__ ovfs_part) {
  __shared__ unsigned int lds[2 * (TROWS / 2) * LSTRIDE];  // ~33.8 KB double-buffered
  const int blk = blockIdx.x;
  const int k = blk >> 2, quarter = blk & 3;
  const int cnt_full = counts[k];
  const int T = cnt_full < PAD_R ? cnt_full : PAD_R;
  const int r_base = quarter * QROWS;
  const int rend = (T < r_base + QROWS) ? T : (r_base + QROWS);
  const int nr = rend - r_base;
  const int nt = (nr > 0) ? ((nr + TROWS - 1) / TROWS) : 0;

  const int tid = threadIdx.x;
  const int lane = tid & 63;
  const int w = tid >> 6;                  // wave 0..7
  const int wr = w >> 1, wc = w & 1;       // wave tile: rows wr*32.., cols wc*64..
  const int p = tid >> 5;                  // quad-row 0..15 (rows 4p..4p+3)
  const int lc = tid & 31;                 // 8B column slice (cols 4lc..4lc+3)

  f32x4 acc[2][4];
  #pragma unroll
  for (int i = 0; i < 2; ++i)
    #pragma unroll
    for (int j = 0; j < 4; ++j) acc[i][j] = (f32x4){0.f, 0.f, 0.f, 0.f};
  float sum4[4] = {0.f, 0.f, 0.f, 0.f}, sq4[4] = {0.f, 0.f, 0.f, 0.f};

  const unsigned int* xgk = xg + (size_t)k * PAD2 * 64;

  // tile t: thread reads rows 4p..4p+3, words 2lc..2lc+1 (cols 4lc..4lc+3). streaming.
  auto load_tile = [&](int t, uint2* vv) {
    const unsigned int* srow = xgk + (size_t)(r_base + t * TROWS + 4 * p) * 64 + lc * 2;
    vv[0] = *(const uint2*)(srow);
    vv[1] = *(const uint2*)(srow + 64);
    vv[2] = *(const uint2*)(srow + 128);
    vv[3] = *(const uint2*)(srow + 192);
  };

  // mask tail rows, accumulate bf16 stats, repack row-pairs, 2x b128 LDS store
  auto write_tile = [&](unsigned int* buf, const uint2* vv, int t) {
    const int rg = r_base + t * TROWS + 4 * p;
    const uint2 z = make_uint2(0u, 0u);
    uint2 r0 = (rg + 0 < rend) ? vv[0] : z;
    uint2 r1 = (rg + 1 < rend) ? vv[1] : z;
    uint2 r2 = (rg + 2 < rend) ? vv[2] : z;
    uint2 r3 = (rg + 3 < rend) ? vv[3] : z;
    sum4[0] += bflo(r0.x) + bflo(r1.x) + bflo(r2.x) + bflo(r3.x);
    sum4[1] += bfhi(r0.x) + bfhi(r1.x) + bfhi(r2.x) + bfhi(r3.x);
    sum4[2] += bflo(r0.y) + bflo(r1.y) + bflo(r2.y) + bflo(r3.y);
    sum4[3] += bfhi(r0.y) + bfhi(r1.y) + bfhi(r2.y) + bfhi(r3.y);
    sq4[0] += bflo(r0.x) * bflo(r0.x) + bflo(r1.x) * bflo(r1.x) + bflo(r2.x) * bflo(r2.x) + bflo(r3.x) * bflo(r3.x);
    sq4[1] += bfhi(r0.x) * bfhi(r0.x) + bfhi(r1.x) * bfhi(r1.x) + bfhi(r2.x) * bfhi(r2.x) + bfhi(r3.x) * bfhi(r3.x);
    sq4[2] += bflo(r0.y) * bflo(r0.y) + bflo(r1.y) * bflo(r1.y) + bflo(r2.y) * bflo(r2.y) + bflo(r3.y) * bflo(r3.y);
    sq4[3] += bfhi(r0.y) * bfhi(r0.y) + bfhi(r1.y) * bfhi(r1.y) + bfhi(r2.y) * bfhi(r2.y) + bfhi(r3.y) * bfhi(r3.y);
    // pair A = rows(4p,4p+1) -> lds row 2p; pair B = rows(4p+2,4p+3) -> lds row 2p+1
    uint4 pa, pb;
    pa.x = (r0.x & 0xffffu) | (r1.x << 16);
    pa.y = (r0.x >> 16) | (r1.x & 0xffff0000u);
    pa.z = (r0.y & 0xffffu) | (r1.y << 16);
    pa.w = (r0.y >> 16) | (r1.y & 0xffff0000u);
    pb.x = (r2.x & 0xffffu) | (r3.x << 16);
    pb.y = (r2.x >> 16) | (r3.x & 0xffff0000u);
    pb.z = (r2.y & 0xffffu) | (r3.y << 16);
    pb.w = (r2.y >> 16) | (r3.y & 0xffff0000u);
    *(uint4*)(&buf[(2 * p) * LSTRIDE + (lc << 2)]) = pa;
    *(uint4*)(&buf[(2 * p + 1) * LSTRIDE + (lc << 2)]) = pb;
  };

  auto compute_tile = [&](const unsigned int* buf) {
    const int q2 = lane >> 4;
    const int fr = lane & 15;
    #pragma unroll
    for (int s = 0; s < 2; ++s) {          // two K=32 steps per 64-row tile
      const unsigned int* base = buf + (s * 16 + q2 * 4) * LSTRIDE;
      bf16x8 afr[2], bfr[4];
      #pragma unroll
      for (int mi = 0; mi < 2; ++mi) {
        const int c = wr * 32 + mi * 16 + fr;
        union { int4 i; bf16x8 h; } u;
        u.i.x = base[0 * LSTRIDE + c];
        u.i.y = base[1 * LSTRIDE + c];
        u.i.z = base[2 * LSTRIDE + c];
        u.i.w = base[3 * LSTRIDE + c];
        afr[mi] = u.h;
      }
      #pragma unroll
      for (int ni = 0; ni < 4; ++ni) {
        const int d = wc * 64 + ni * 16 + fr;
        union { int4 i; bf16x8 h; } u;
        u.i.x = base[0 * LSTRIDE + d];
        u.i.y = base[1 * LSTRIDE + d];
        u.i.z = base[2 * LSTRIDE + d];
        u.i.w = base[3 * LSTRIDE + d];
        bfr[ni] = u.h;
      }
      #pragma unroll
      for (int mi = 0; mi < 2; ++mi)
        #pragma unroll
        for (int ni = 0; ni < 4; ++ni)
          acc[mi][ni] = __builtin_amdgcn_mfma_f32_16x16x32_bf16(afr[mi], bfr[ni], acc[mi][ni], 0, 0, 0);
    }
  };

  const int BUFSZ = (TROWS / 2) * LSTRIDE;
  if (nt > 0) {
    uint2 vA[4], vB[4];
    load_tile(0, vA);
    if (nt > 1) load_tile(1, vB);
    write_tile(lds, vA, 0);
    if (nt > 2) load_tile(2, vA);
    TILE_BARRIER();
    int cur = 0;
    for (int t = 0; t < nt; t += 2) {
      if (t + 1 < nt) {
        write_tile(lds + (unsigned)(cur ^ 1) * BUFSZ, vB, t + 1);
        if (t + 3 < nt) load_tile(t + 3, vB);
      }
      compute_tile(lds + (unsigned)cur * BUFSZ);
      TILE_BARRIER();
      cur ^= 1;
      if (t + 1 >= nt) break;
      if (t + 2 < nt) {
        write_tile(lds + (unsigned)(cur ^ 1) * BUFSZ, vA, t + 2);
        if (t + 4 < nt) load_tile(t + 4, vA);
      }
      compute_tile(lds + (unsigned)cur * BUFSZ);
      TILE_BARRIER();
      cur ^= 1;
    }
  }

  // ---- overflow rows (r >= PAD_R): full-stat contribution only, streaming bf16 ----
  float osum[4] = {0.f, 0.f, 0.f, 0.f}, osq[4] = {0.f, 0.f, 0.f, 0.f};
  for (int r = PAD_R + quarter + (p << 2); r < cnt_full; r += 64) {
    uint2 v = *(const uint2*)(xgk + (size_t)r * 64 + lc * 2);
    float f0 = bflo(v.x), f1 = bfhi(v.x), f2 = bflo(v.y), f3 = bfhi(v.y);
    osum[0] += f0; osq[0] += f0 * f0;
    osum[1] += f1; osq[1] += f1 * f1;
    osum[2] += f2; osq[2] += f2 * f2;
    osum[3] += f3; osq[3] += f3 * f3;
  }

  // ---- epilogue: reduce trunc-sum / full-sq / ovf-sum, store partial S ----
  __syncthreads();
  float* red = (float*)lds;
  const int colo = lc << 2;
  if (tid < 3 * C_DIM) red[tid] = 0.f;
  __syncthreads();
  #pragma unroll
  for (int e = 0; e < 4; ++e) {
    atomicAdd(&red[colo + e], sum4[e]);
    atomicAdd(&red[C_DIM + colo + e], sq4[e] + osq[e]);
    atomicAdd(&red[2 * C_DIM + colo + e], osum[e]);
  }
  __syncthreads();
  if (tid < C_DIM) {
    sums_part[(quarter * K_CLS + k) * C_DIM + tid] = red[tid];
    sqs_part [(quarter * K_CLS + k) * C_DIM + tid] = red[C_DIM + tid];
    ovfs_part[(quarter * K_CLS + k) * C_DIM + tid] = red[2 * C_DIM + tid];
  }
  float* sp = spart + (size_t)(quarter * K_CLS + k) * (C_DIM * C_DIM);
  #pragma unroll
  for (int mi = 0; mi < 2; ++mi)
    #pragma unroll
    for (int ni = 0; ni < 4; ++ni)
      #pragma unroll
      for (int r = 0; r < 4; ++r) {
        int c = wr * 32 + mi * 16 + ((lane >> 4) << 2) + r;
        int d = wc * 64 + ni * 16 + (lane & 15);
        sp[c * C_DIM + d] = acc[mi][ni][r];
      }
}

// ---------------- per-class analytic corr, off-diag^2 reduction (4 blocks/class) ----------------
__global__ __launch_bounds__(512) void finalize_kernel(const float* __restrict__ spart,
                                                       const float* __restrict__ sums_part,
                                                       const float* __restrict__ sqs_part,
                                                       const float* __restrict__ ovfs_part,
                                                       const int* __restrict__ counts,
                                                       float* __restrict__ numden) {
  __shared__ float m_l[C_DIM], is_l[C_DIM], st_l[C_DIM];
  __shared__ float wred[8];
  const int k = blockIdx.x >> 2, fs = blockIdx.x & 3;
  const int tid = threadIdx.x;
  const int count = counts[k];
  const float Tf = (float)(count < PAD_R ? count : PAD_R);
  if (tid < C_DIM) {
    float s_tr = 0.f, osum = 0.f, fsq = 0.f;
    #pragma unroll
    for (int j = 0; j < QSPLIT; ++j) {
      s_tr += sums_part[(j * K_CLS + k) * C_DIM + tid];
      osum += ovfs_part[(j * K_CLS + k) * C_DIM + tid];
      fsq  += sqs_part [(j * K_CLS + k) * C_DIM + tid];
    }
    float fsum = s_tr + osum;
    float cf = (float)count;
    float m = fsum / fmaxf(cf, 1.f);
    float var = (fsq - cf * m * m) / fmaxf(cf - 1.f, 1.f);
    m_l[tid] = m;
    is_l[tid] = rsqrtf(var + EPS_F);
    st_l[tid] = s_tr;
  }
  __syncthreads();
  float local = 0.f;
  const int e_lo = fs * (C_DIM * C_DIM / FSPLIT);
  const int e_hi = e_lo + (C_DIM * C_DIM / FSPLIT);
  for (int e4 = e_lo + tid * 4; e4 < e_hi; e4 += 512 * 4) {
    int c = e4 >> 7, d0 = e4 & 127;
    f32x4 sa = (f32x4){0.f, 0.f, 0.f, 0.f};
    #pragma unroll
    for (int j = 0; j < QSPLIT; ++j) {
      f32x4 sj = *(const f32x4*)(spart + (size_t)(j * K_CLS + k) * (C_DIM * C_DIM) + e4);
      #pragma unroll
      for (int e = 0; e < 4; ++e) sa[e] += sj[e];
    }
    #pragma unroll
    for (int e = 0; e < 4; ++e) {
      int d = d0 + e;
      float corr = is_l[c] * is_l[d] *
                   (sa[e] - m_l[c] * st_l[d] - m_l[d] * st_l[c] + Tf * m_l[c] * m_l[d]);
      if (c != d) local += corr * corr;
    }
  }
  for (int off = 32; off > 0; off >>= 1) local += __shfl_down(local, off);
  int lane = tid & 63, wid = tid >> 6;
  if (lane == 0) wred[wid] = local;
  __syncthreads();
  if (tid == 0 && count > 1) {
    float tot = 0.f;
    #pragma unroll
    for (int i = 0; i < 8; ++i) tot += wred[i];
    atomicAdd(&numden[0], tot * (1.f / (float)(C_DIM * (C_DIM - 1))));
    if (fs == 0) atomicAdd(&numden[1], (float)count);
  }
}

__global__ void div_kernel(const float* __restrict__ numden, float* __restrict__ out) {
  if (threadIdx.x == 0 && blockIdx.x == 0)
    out[0] = numden[1] > 0.f ? numden[0] / numden[1] : 0.f;
}

// ---------------- workspace layout (ws_size = 512 MB) ----------------
// [0,256)              numden
// [256, +128K)         hist
// [131328, +512)       counts
// [132096, +128M)      xg (128 * 4096 * 256B bf16 rows)
// [134349824, +256K)   sums_part (4 * 128 * 128 * 4)
// [134611968, +256K)   sqs_part
// [134874112, +256K)   ovfs_part
// [135136256, +32M)    spart (4 * 128 * 64KB)
extern "C" void kernel_launch(void* const* d_in, const int* in_sizes, int n_in,
                              void* d_out, int out_size, void* d_ws, size_t ws_size,
                              hipStream_t stream) {
  (void)in_sizes; (void)n_in; (void)out_size; (void)ws_size;
  const float* x = (const float*)d_in[0];
  const int*   y = (const int*)d_in[1];
  float* out = (float*)d_out;
  char* ws = (char*)d_ws;

  float*        numden    = (float*)(ws + 0);
  int*          hist      = (int*)(ws + 256);
  int*          counts    = (int*)(ws + 131328);
  unsigned int* xg        = (unsigned int*)(ws + 132096);
  float*        sums_part = (float*)(ws + 134349824);
  float*        sqs_part  = (float*)(ws + 134611968);
  float*        ovfs_part = (float*)(ws + 134874112);
  float*        spart     = (float*)(ws + 135136256);

  hist_kernel<<<G_CHUNKS, 256, 0, stream>>>(y, hist, numden);
  scan_kernel<<<K_CLS, 256, 0, stream>>>(hist, counts);
  scatter_kernel<<<G_CHUNKS, 1024, 0, stream>>>(x, y, hist, xg);
  gemm_kernel<<<QSPLIT * K_CLS, 512, 0, stream>>>(xg, counts, spart, sums_part,
                                                  sqs_part, ovfs_part);
  finalize_kernel<<<FSPLIT * K_CLS, 512, 0, stream>>>(spart, sums_part, sqs_part,
                                                      ovfs_part, counts, numden);
  div_kernel<<<1, 64, 0, stream>>>(numden, out);
}

// Round 13
// 83.196 us; speedup vs baseline: 1.4597x; 1.4597x over previous
//
#include <hip/hip_runtime.h>

#define B_ROWS   262144
#define C_DIM    128
#define K_CLS    128
#define PAD_R    2048
#define PAD2     4096
#define QSPLIT   4
#define QROWS    (PAD_R / QSPLIT)
#define FSPLIT   4
#define TROWS    64
#define EPS_F    1e-8f
#define CHUNK    1024
#define G_CHUNKS 256

typedef float f32x4  __attribute__((ext_vector_type(4)));
typedef float f32x16 __attribute__((ext_vector_type(16)));
typedef short bf16x8 __attribute__((ext_vector_type(8)));

__device__ __forceinline__ unsigned f2bf(float f) {
  unsigned u = __float_as_uint(f);
  return (u + 0x7fffu + ((u >> 16) & 1u)) >> 16;   // RNE bf16
}
__device__ __forceinline__ unsigned packbf(float a, float b) {
  return f2bf(a) | (f2bf(b) << 16);
}
// bank swizzle: write side (c=4lc+e) spreads 8 groups; read side conflict-free per 8-lane phase
__device__ __forceinline__ int swz(int c) { return ((c >> 2) ^ c) & 7; }
__device__ __forceinline__ int lidx(int c, int kp) {
  return c * 32 + ((((kp >> 2) ^ swz(c)) << 2) | (kp & 3));
}

// lgkm-only barrier: LDS visibility without draining global-load vmcnt
#define TILE_BARRIER()                                      \
  do {                                                      \
    asm volatile("s_waitcnt lgkmcnt(0)" ::: "memory");      \
    __builtin_amdgcn_s_barrier();                           \
  } while (0)

// ---------------- histogram over 1024-row chunks (+ numden zero) ----------------
__global__ __launch_bounds__(256) void hist_kernel(const int* __restrict__ y,
                                                   int* __restrict__ hist,
                                                   float* __restrict__ numden) {
  __shared__ int h[K_CLS];
  int g = blockIdx.x, tid = threadIdx.x;
  if (g == 0 && tid < 64) numden[tid] = 0.f;
  if (tid < K_CLS) h[tid] = 0;
  __syncthreads();
  for (int j = tid; j < CHUNK; j += 256) atomicAdd(&h[y[g * CHUNK + j]], 1);
  __syncthreads();
  if (tid < K_CLS) hist[g * K_CLS + tid] = h[tid];
}

// ---------------- per-class exclusive scan over chunks ----------------
__global__ __launch_bounds__(256) void scan_kernel(int* __restrict__ hist,
                                                   int* __restrict__ counts) {
  __shared__ int s[G_CHUNKS];
  int k = blockIdx.x, g = threadIdx.x;
  int v = hist[g * K_CLS + k];
  s[g] = v;
  __syncthreads();
  for (int off = 1; off < G_CHUNKS; off <<= 1) {
    int t = (g >= off) ? s[g - off] : 0;
    __syncthreads();
    s[g] += t;
    __syncthreads();
  }
  hist[g * K_CLS + k] = s[g] - v;          // exclusive prefix
  if (g == G_CHUNKS - 1) counts[k] = s[g]; // total count
}

// ---------------- parallel stable ranks -> ord[] (no atomics, no x) ----------------
__global__ __launch_bounds__(256) void rank_kernel(const int* __restrict__ y,
                                                   const int* __restrict__ hist,
                                                   int* __restrict__ ord) {
  __shared__ unsigned short cnt_sub[16][K_CLS];
  __shared__ int offs[K_CLS];
  const int g = blockIdx.x, tid = threadIdx.x;
  const int lane = tid & 63, w = tid >> 6;
  if (tid < K_CLS) offs[tid] = hist[g * K_CLS + tid];
  {
    unsigned int* cz = (unsigned int*)cnt_sub;
    for (int i = tid; i < 16 * K_CLS / 2; i += 256) cz[i] = 0;
  }
  __syncthreads();

  int yv[4], rig[4];
  #pragma unroll
  for (int i = 0; i < 4; ++i) {
    const int s = w * 4 + i;
    const int yy = y[g * CHUNK + s * 64 + lane];
    unsigned long long m = ~0ULL;
    #pragma unroll
    for (int b = 0; b < 7; ++b) {
      unsigned long long bb = __ballot((yy >> b) & 1);
      m &= ((yy >> b) & 1) ? bb : ~bb;
    }
    const unsigned long long lt = (1ULL << lane) - 1ULL;
    rig[i] = (int)__popcll(m & lt);
    yv[i] = yy;
    const int leader = __ffsll((long long)m) - 1;
    if (lane == leader) cnt_sub[s][yy] = (unsigned short)__popcll(m);
  }
  __syncthreads();

  if (tid < K_CLS) {
    int run = 0;
    #pragma unroll
    for (int s = 0; s < 16; ++s) {
      int t = cnt_sub[s][tid];
      cnt_sub[s][tid] = (unsigned short)run;
      run += t;
    }
  }
  __syncthreads();

  #pragma unroll
  for (int i = 0; i < 4; ++i) {
    const int s = w * 4 + i;
    const int k = yv[i];
    const int R = offs[k] + (int)cnt_sub[s][k] + rig[i];
    if (R < PAD2) ord[k * PAD2 + R] = g * CHUNK + s * 64 + lane;
  }
}

// ---------------- per-class X^T X via 32x32x16 MFMA, 4 blocks/class, 64-row tiles ----------------
// LDS [c][kp] u32, kp = k/2 pair; idx = c*32 + (((kp>>2)^swz(c))<<2 | (kp&3)).
//   write: ds_write_b64 per col, 8 bank-groups (free)
//   read : ds_read_b128 frag (8 consecutive k), conflict-free per 8-lane phase
// 8 waves; wave w -> output quadrant rows qr*32 (qr=w>>1), cols qc*64 (qc=w&1).
__global__ __launch_bounds__(512, 4) void gemm_kernel(const float* __restrict__ x,
                                                      const int* __restrict__ ord,
                                                      const int* __restrict__ counts,
                                                      float* __restrict__ spart,
                                                      float* __restrict__ sums_part,
                                                      float* __restrict__ sqs_part,
                                                      float* __restrict__ ovfs_part) {
  __shared__ unsigned int lds[2 * C_DIM * 32];   // 2 x 16KB double-buffered
  __shared__ int ord_l[QROWS];                   // 2KB staged indices
  const int blk = blockIdx.x;
  const int k = blk >> 2, quarter = blk & 3;
  const int cnt_full = counts[k];
  const int T = cnt_full < PAD_R ? cnt_full : PAD_R;
  const int r_base = quarter * QROWS;
  const int rend = (T < r_base + QROWS) ? T : (r_base + QROWS);
  const int nr = rend - r_base;
  const int nt = (nr > 0) ? ((nr + TROWS - 1) / TROWS) : 0;

  const int tid = threadIdx.x;
  const int lane = tid & 63;
  const int w = tid >> 6;                  // wave 0..7
  const int qr = w >> 1, qc = w & 1;       // quadrant rows qr*32, cols qc*64
  const int p = tid >> 5;                  // row-quad 0..15 (local rows 4p..4p+3)
  const int lc = tid & 31;                 // 16B col slice

  f32x16 acc[2];
  #pragma unroll
  for (int i = 0; i < 2; ++i)
    #pragma unroll
    for (int j = 0; j < 16; ++j) acc[i][j] = 0.f;
  float sum4[4] = {0.f, 0.f, 0.f, 0.f}, sq4[4] = {0.f, 0.f, 0.f, 0.f};

  const int* ordk = ord + k * PAD2;

  {
    int vi = ordk[r_base + tid];
    ord_l[tid] = ((unsigned)vi < B_ROWS) ? vi : 0;   // clamp poison/stale
  }
  __syncthreads();

  // unconditional gather (masking deferred to write_tile)
  auto load_tile = [&](int t, f32x4* vv) {
    const int rr = t * TROWS + 4 * p;
    const int4 idx = *(const int4*)(&ord_l[rr]);
    const size_t co = (size_t)(lc << 2);
    vv[0] = *(const f32x4*)(x + (size_t)idx.x * C_DIM + co);
    vv[1] = *(const f32x4*)(x + (size_t)idx.y * C_DIM + co);
    vv[2] = *(const f32x4*)(x + (size_t)idx.z * C_DIM + co);
    vv[3] = *(const f32x4*)(x + (size_t)idx.w * C_DIM + co);
  };

  // mask tail rows, stats, pack pairs, one b64 write per col
  auto write_tile = [&](unsigned int* buf, const f32x4* vv, int t) {
    const int rg = r_base + t * TROWS + 4 * p;
    const f32x4 z = (f32x4){0.f, 0.f, 0.f, 0.f};
    const f32x4 w0 = (rg + 0 < rend) ? vv[0] : z;
    const f32x4 w1 = (rg + 1 < rend) ? vv[1] : z;
    const f32x4 w2 = (rg + 2 < rend) ? vv[2] : z;
    const f32x4 w3 = (rg + 3 < rend) ? vv[3] : z;
    #pragma unroll
    for (int e = 0; e < 4; ++e) {
      sum4[e] += (w0[e] + w1[e]) + (w2[e] + w3[e]);
      sq4[e] += (w0[e] * w0[e] + w1[e] * w1[e]) + (w2[e] * w2[e] + w3[e] * w3[e]);
    }
    #pragma unroll
    for (int e = 0; e < 4; ++e) {
      const int c = (lc << 2) + e;
      uint2 pk;
      pk.x = packbf(w0[e], w1[e]);       // kp = 2p
      pk.y = packbf(w2[e], w3[e]);       // kp = 2p+1 (same 16B group)
      *(uint2*)(&buf[lidx(c, 2 * p)]) = pk;
    }
  };

  auto compute_tile = [&](const unsigned int* buf) {
    const int h = lane >> 5;
    const int r32 = lane & 31;
    #pragma unroll
    for (int s = 0; s < 4; ++s) {          // four K=16 steps per 64-row tile
      const int kp0 = 8 * s + 4 * h;       // b128: kp0..kp0+3 -> k 16s+8h..+7
      const int cA = qr * 32 + r32;
      bf16x8 a = *(const bf16x8*)(&buf[lidx(cA, kp0)]);
      #pragma unroll
      for (int ni = 0; ni < 2; ++ni) {
        const int dB = qc * 64 + ni * 32 + r32;
        bf16x8 b = *(const bf16x8*)(&buf[lidx(dB, kp0)]);
        acc[ni] = __builtin_amdgcn_mfma_f32_32x32x16_bf16(a, b, acc[ni], 0, 0, 0);
      }
    }
  };

  const int BUFSZ = C_DIM * 32;
  if (nt > 0) {
    f32x4 vA[4], vB[4];
    load_tile(0, vA);
    if (nt > 1) load_tile(1, vB);
    write_tile(lds, vA, 0);
    if (nt > 2) load_tile(2, vA);
    TILE_BARRIER();
    int cur = 0;
    for (int t = 0; t < nt; t += 2) {
      if (t + 1 < nt) {
        write_tile(lds + (unsigned)(cur ^ 1) * BUFSZ, vB, t + 1);
        if (t + 3 < nt) load_tile(t + 3, vB);
      }
      compute_tile(lds + (unsigned)cur * BUFSZ);
      TILE_BARRIER();
      cur ^= 1;
      if (t + 1 >= nt) break;
      if (t + 2 < nt) {
        write_tile(lds + (unsigned)(cur ^ 1) * BUFSZ, vA, t + 2);
        if (t + 4 < nt) load_tile(t + 4, vA);
      }
      compute_tile(lds + (unsigned)cur * BUFSZ);
      TILE_BARRIER();
      cur ^= 1;
    }
  }

  // ---- overflow rows (r >= PAD_R): full-stat contribution only, coalesced ----
  float osum[4] = {0.f, 0.f, 0.f, 0.f}, osq[4] = {0.f, 0.f, 0.f, 0.f};
  const int colo = lc << 2;
  for (int r = PAD_R + quarter + (p << 2); r < cnt_full; r += 64) {
    int row = ordk[r];
    f32x4 vv = *(const f32x4*)(x + (size_t)row * C_DIM + colo);
    #pragma unroll
    for (int e = 0; e < 4; ++e) { float t = vv[e]; osum[e] += t; osq[e] += t * t; }
  }

  // ---- epilogue: reduce trunc-sum / full-sq / ovf-sum, store partial S ----
  __syncthreads();
  float* red = (float*)lds;
  if (tid < 3 * C_DIM) red[tid] = 0.f;
  __syncthreads();
  #pragma unroll
  for (int e = 0; e < 4; ++e) {
    atomicAdd(&red[colo + e], sum4[e]);
    atomicAdd(&red[C_DIM + colo + e], sq4[e] + osq[e]);
    atomicAdd(&red[2 * C_DIM + colo + e], osum[e]);
  }
  __syncthreads();
  if (tid < C_DIM) {
    sums_part[(quarter * K_CLS + k) * C_DIM + tid] = red[tid];
    sqs_part [(quarter * K_CLS + k) * C_DIM + tid] = red[C_DIM + tid];
    ovfs_part[(quarter * K_CLS + k) * C_DIM + tid] = red[2 * C_DIM + tid];
  }
  // C/D (measured m74/m101): col = lane&31, row = (reg&3) + 8*(reg>>2) + 4*(lane>>5)
  float* sp = spart + (size_t)(quarter * K_CLS + k) * (C_DIM * C_DIM);
  {
    const int h = lane >> 5, r32 = lane & 31;
    #pragma unroll
    for (int ni = 0; ni < 2; ++ni)
      #pragma unroll
      for (int r = 0; r < 16; ++r) {
        int c = qr * 32 + (r & 3) + 8 * (r >> 2) + 4 * h;
        int d = qc * 64 + ni * 32 + r32;
        sp[c * C_DIM + d] = acc[ni][r];
      }
  }
}

// ---------------- per-class analytic corr, off-diag^2 reduction (4 blocks/class) ----------------
__global__ __launch_bounds__(512) void finalize_kernel(const float* __restrict__ spart,
                                                       const float* __restrict__ sums_part,
                                                       const float* __restrict__ sqs_part,
                                                       const float* __restrict__ ovfs_part,
                                                       const int* __restrict__ counts,
                                                       float* __restrict__ numden) {
  __shared__ float m_l[C_DIM], is_l[C_DIM], st_l[C_DIM];
  __shared__ float wred[8];
  const int k = blockIdx.x >> 2, fs = blockIdx.x & 3;
  const int tid = threadIdx.x;
  const int count = counts[k];
  const float Tf = (float)(count < PAD_R ? count : PAD_R);
  if (tid < C_DIM) {
    float s_tr = 0.f, osum = 0.f, fsq = 0.f;
    #pragma unroll
    for (int j = 0; j < QSPLIT; ++j) {
      s_tr += sums_part[(j * K_CLS + k) * C_DIM + tid];
      osum += ovfs_part[(j * K_CLS + k) * C_DIM + tid];
      fsq  += sqs_part [(j * K_CLS + k) * C_DIM + tid];
    }
    float fsum = s_tr + osum;
    float cf = (float)count;
    float m = fsum / fmaxf(cf, 1.f);
    float var = (fsq - cf * m * m) / fmaxf(cf - 1.f, 1.f);
    m_l[tid] = m;
    is_l[tid] = rsqrtf(var + EPS_F);
    st_l[tid] = s_tr;
  }
  __syncthreads();
  float local = 0.f;
  const int e_lo = fs * (C_DIM * C_DIM / FSPLIT);
  const int e_hi = e_lo + (C_DIM * C_DIM / FSPLIT);
  for (int e4 = e_lo + tid * 4; e4 < e_hi; e4 += 512 * 4) {
    int c = e4 >> 7, d0 = e4 & 127;
    f32x4 sa = (f32x4){0.f, 0.f, 0.f, 0.f};
    #pragma unroll
    for (int j = 0; j < QSPLIT; ++j) {
      f32x4 sj = *(const f32x4*)(spart + (size_t)(j * K_CLS + k) * (C_DIM * C_DIM) + e4);
      #pragma unroll
      for (int e = 0; e < 4; ++e) sa[e] += sj[e];
    }
    #pragma unroll
    for (int e = 0; e < 4; ++e) {
      int d = d0 + e;
      float corr = is_l[c] * is_l[d] *
                   (sa[e] - m_l[c] * st_l[d] - m_l[d] * st_l[c] + Tf * m_l[c] * m_l[d]);
      if (c != d) local += corr * corr;
    }
  }
  for (int off = 32; off > 0; off >>= 1) local += __shfl_down(local, off);
  int lane = tid & 63, wid = tid >> 6;
  if (lane == 0) wred[wid] = local;
  __syncthreads();
  if (tid == 0 && count > 1) {
    float tot = 0.f;
    #pragma unroll
    for (int i = 0; i < 8; ++i) tot += wred[i];
    atomicAdd(&numden[0], tot * (1.f / (float)(C_DIM * (C_DIM - 1))));
    if (fs == 0) atomicAdd(&numden[1], (float)count);
  }
}

__global__ void div_kernel(const float* __restrict__ numden, float* __restrict__ out) {
  if (threadIdx.x == 0 && blockIdx.x == 0)
    out[0] = numden[1] > 0.f ? numden[0] / numden[1] : 0.f;
}

// ---------------- workspace layout (ws_size = 512 MB) ----------------
// [0,256)            numden
// [256, +128K)       hist
// [131328, +512)     counts
// [132096, +2M)      ord (128 * 4096 * 4)
// [2229248, +256K)   sums_part (4 * 128 * 128 * 4)
// [2491392, +256K)   sqs_part
// [2753536, +256K)   ovfs_part
// [3015680, +32M)    spart (4 * 128 * 64KB)
extern "C" void kernel_launch(void* const* d_in, const int* in_sizes, int n_in,
                              void* d_out, int out_size, void* d_ws, size_t ws_size,
                              hipStream_t stream) {
  (void)in_sizes; (void)n_in; (void)out_size; (void)ws_size;
  const float* x = (const float*)d_in[0];
  const int*   y = (const int*)d_in[1];
  float* out = (float*)d_out;
  char* ws = (char*)d_ws;

  float* numden    = (float*)(ws + 0);
  int*   hist      = (int*)(ws + 256);
  int*   counts    = (int*)(ws + 131328);
  int*   ord       = (int*)(ws + 132096);
  float* sums_part = (float*)(ws + 2229248);
  float* sqs_part  = (float*)(ws + 2491392);
  float* ovfs_part = (float*)(ws + 2753536);
  float* spart     = (float*)(ws + 3015680);

  hist_kernel<<<G_CHUNKS, 256, 0, stream>>>(y, hist, numden);
  scan_kernel<<<K_CLS, 256, 0, stream>>>(hist, counts);
  rank_kernel<<<G_CHUNKS, 256, 0, stream>>>(y, hist, ord);
  gemm_kernel<<<QSPLIT * K_CLS, 512, 0, stream>>>(x, ord, counts, spart, sums_part,
                                                  sqs_part, ovfs_part);
  finalize_kernel<<<FSPLIT * K_CLS, 512, 0, stream>>>(spart, sums_part, sqs_part,
                                                      ovfs_part, counts, numden);
  div_kernel<<<1, 64, 0, stream>>>(numden, out);
}

// Round 14
// 65.572 us; speedup vs baseline: 1.8520x; 1.2688x over previous
//
#include <hip/hip_runtime.h>

#define B_ROWS   262144
#define C_DIM    128
#define K_CLS    128
#define PAD_R    2048
#define PAD2     4096
#define QSPLIT   2
#define QROWS    (PAD_R / QSPLIT)
#define FSPLIT   4
#define TROWS    64
#define EPS_F    1e-8f
#define CHUNK    1024
#define G_CHUNKS 256

typedef float f32x4  __attribute__((ext_vector_type(4)));
typedef float f32x16 __attribute__((ext_vector_type(16)));
typedef short bf16x8 __attribute__((ext_vector_type(8)));

__device__ __forceinline__ unsigned f2bf(float f) {
  unsigned u = __float_as_uint(f);
  return (u + 0x7fffu + ((u >> 16) & 1u)) >> 16;   // RNE bf16
}
__device__ __forceinline__ unsigned packbf(float a, float b) {
  return f2bf(a) | (f2bf(b) << 16);
}
__device__ __forceinline__ int swz(int c) { return ((c >> 2) ^ c) & 7; }
__device__ __forceinline__ int lidx(int c, int kp) {
  return c * 32 + ((((kp >> 2) ^ swz(c)) << 2) | (kp & 3));
}

// lgkm-only barrier: LDS visibility without draining global-load vmcnt --
// keeps the depth-4 prefetch loads in flight across tiles.
#define TILE_BARRIER()                                      \
  do {                                                      \
    asm volatile("s_waitcnt lgkmcnt(0)" ::: "memory");      \
    __builtin_amdgcn_s_barrier();                           \
  } while (0)

// ---------------- histogram over 1024-row chunks (+ numden zero) ----------------
__global__ __launch_bounds__(256) void hist_kernel(const int* __restrict__ y,
                                                   int* __restrict__ hist,
                                                   float* __restrict__ numden) {
  __shared__ int h[K_CLS];
  int g = blockIdx.x, tid = threadIdx.x;
  if (g == 0 && tid < 64) numden[tid] = 0.f;
  if (tid < K_CLS) h[tid] = 0;
  __syncthreads();
  for (int j = tid; j < CHUNK; j += 256) atomicAdd(&h[y[g * CHUNK + j]], 1);
  __syncthreads();
  if (tid < K_CLS) hist[g * K_CLS + tid] = h[tid];
}

// ---------------- per-class exclusive scan over chunks ----------------
__global__ __launch_bounds__(256) void scan_kernel(int* __restrict__ hist,
                                                   int* __restrict__ counts) {
  __shared__ int s[G_CHUNKS];
  int k = blockIdx.x, g = threadIdx.x;
  int v = hist[g * K_CLS + k];
  s[g] = v;
  __syncthreads();
  for (int off = 1; off < G_CHUNKS; off <<= 1) {
    int t = (g >= off) ? s[g - off] : 0;
    __syncthreads();
    s[g] += t;
    __syncthreads();
  }
  hist[g * K_CLS + k] = s[g] - v;          // exclusive prefix
  if (g == G_CHUNKS - 1) counts[k] = s[g]; // total count
}

// ---------------- parallel stable ranks -> ord[] (no atomics, no x) ----------------
__global__ __launch_bounds__(256) void rank_kernel(const int* __restrict__ y,
                                                   const int* __restrict__ hist,
                                                   int* __restrict__ ord) {
  __shared__ unsigned short cnt_sub[16][K_CLS];
  __shared__ int offs[K_CLS];
  const int g = blockIdx.x, tid = threadIdx.x;
  const int lane = tid & 63, w = tid >> 6;
  if (tid < K_CLS) offs[tid] = hist[g * K_CLS + tid];
  {
    unsigned int* cz = (unsigned int*)cnt_sub;
    for (int i = tid; i < 16 * K_CLS / 2; i += 256) cz[i] = 0;
  }
  __syncthreads();

  int yv[4], rig[4];
  #pragma unroll
  for (int i = 0; i < 4; ++i) {
    const int s = w * 4 + i;
    const int yy = y[g * CHUNK + s * 64 + lane];
    unsigned long long m = ~0ULL;
    #pragma unroll
    for (int b = 0; b < 7; ++b) {
      unsigned long long bb = __ballot((yy >> b) & 1);
      m &= ((yy >> b) & 1) ? bb : ~bb;
    }
    const unsigned long long lt = (1ULL << lane) - 1ULL;
    rig[i] = (int)__popcll(m & lt);
    yv[i] = yy;
    const int leader = __ffsll((long long)m) - 1;
    if (lane == leader) cnt_sub[s][yy] = (unsigned short)__popcll(m);
  }
  __syncthreads();

  if (tid < K_CLS) {
    int run = 0;
    #pragma unroll
    for (int s = 0; s < 16; ++s) {
      int t = cnt_sub[s][tid];
      cnt_sub[s][tid] = (unsigned short)run;
      run += t;
    }
  }
  __syncthreads();

  #pragma unroll
  for (int i = 0; i < 4; ++i) {
    const int s = w * 4 + i;
    const int k = yv[i];
    const int R = offs[k] + (int)cnt_sub[s][k] + rig[i];
    if (R < PAD2) ord[k * PAD2 + R] = g * CHUNK + s * 64 + lane;
  }
}

// ---------------- per-class X^T X via 32x32x16 MFMA, 2 blocks/class, 64-row tiles ----------------
// LDS [c][kp] swizzled (R13 layout, verified absmax 0.0, ~0 conflicts).
// Depth-4 register prefetch (v0..v3) + lgkm-only barriers: loads stay in
// flight ~3 compute phases (~1500 cyc) before first use > HBM latency.
__global__ __launch_bounds__(512, 1) void gemm_kernel(const float* __restrict__ x,
                                                      const int* __restrict__ ord,
                                                      const int* __restrict__ counts,
                                                      float* __restrict__ spart,
                                                      float* __restrict__ sums_part,
                                                      float* __restrict__ sqs_part,
                                                      float* __restrict__ ovfs_part) {
  __shared__ unsigned int lds[2 * C_DIM * 32];   // 2 x 16KB double-buffered
  __shared__ int ord_l[QROWS];                   // 4KB staged indices
  const int blk = blockIdx.x;
  const int k = blk >> 1, half = blk & 1;
  const int cnt_full = counts[k];
  const int T = cnt_full < PAD_R ? cnt_full : PAD_R;
  const int r_base = half * QROWS;
  const int rend = (T < r_base + QROWS) ? T : (r_base + QROWS);
  const int nr = rend - r_base;
  const int nt = (nr > 0) ? ((nr + TROWS - 1) / TROWS) : 0;

  const int tid = threadIdx.x;
  const int lane = tid & 63;
  const int w = tid >> 6;                  // wave 0..7
  const int qr = w >> 1, qc = w & 1;       // quadrant rows qr*32, cols qc*64
  const int p = tid >> 5;                  // row-quad 0..15 (local rows 4p..4p+3)
  const int lc = tid & 31;                 // 16B col slice

  f32x16 acc[2];
  #pragma unroll
  for (int i = 0; i < 2; ++i)
    #pragma unroll
    for (int j = 0; j < 16; ++j) acc[i][j] = 0.f;
  float sum4[4] = {0.f, 0.f, 0.f, 0.f}, sq4[4] = {0.f, 0.f, 0.f, 0.f};

  const int* ordk = ord + k * PAD2;

  for (int i = tid; i < QROWS; i += 512) {
    int vi = ordk[r_base + i];
    ord_l[i] = ((unsigned)vi < B_ROWS) ? vi : 0;   // clamp poison/stale
  }
  __syncthreads();

  // unconditional gather (masking deferred to write_tile)
  auto load_tile = [&](int t, f32x4* vv) {
    const int rr = t * TROWS + 4 * p;
    const int4 idx = *(const int4*)(&ord_l[rr]);
    const size_t co = (size_t)(lc << 2);
    vv[0] = *(const f32x4*)(x + (size_t)idx.x * C_DIM + co);
    vv[1] = *(const f32x4*)(x + (size_t)idx.y * C_DIM + co);
    vv[2] = *(const f32x4*)(x + (size_t)idx.z * C_DIM + co);
    vv[3] = *(const f32x4*)(x + (size_t)idx.w * C_DIM + co);
  };

  // mask tail rows, stats, pack pairs, one b64 write per col
  auto write_tile = [&](unsigned int* buf, const f32x4* vv, int t) {
    const int rg = r_base + t * TROWS + 4 * p;
    const f32x4 z = (f32x4){0.f, 0.f, 0.f, 0.f};
    const f32x4 w0 = (rg + 0 < rend) ? vv[0] : z;
    const f32x4 w1 = (rg + 1 < rend) ? vv[1] : z;
    const f32x4 w2 = (rg + 2 < rend) ? vv[2] : z;
    const f32x4 w3 = (rg + 3 < rend) ? vv[3] : z;
    #pragma unroll
    for (int e = 0; e < 4; ++e) {
      sum4[e] += (w0[e] + w1[e]) + (w2[e] + w3[e]);
      sq4[e] += (w0[e] * w0[e] + w1[e] * w1[e]) + (w2[e] * w2[e] + w3[e] * w3[e]);
    }
    #pragma unroll
    for (int e = 0; e < 4; ++e) {
      const int c = (lc << 2) + e;
      uint2 pk;
      pk.x = packbf(w0[e], w1[e]);       // kp = 2p
      pk.y = packbf(w2[e], w3[e]);       // kp = 2p+1
      *(uint2*)(&buf[lidx(c, 2 * p)]) = pk;
    }
  };

  auto compute_tile = [&](const unsigned int* buf) {
    const int h = lane >> 5;
    const int r32 = lane & 31;
    #pragma unroll
    for (int s = 0; s < 4; ++s) {          // four K=16 steps per 64-row tile
      const int kp0 = 8 * s + 4 * h;
      const int cA = qr * 32 + r32;
      bf16x8 a = *(const bf16x8*)(&buf[lidx(cA, kp0)]);
      #pragma unroll
      for (int ni = 0; ni < 2; ++ni) {
        const int dB = qc * 64 + ni * 32 + r32;
        bf16x8 b = *(const bf16x8*)(&buf[lidx(dB, kp0)]);
        acc[ni] = __builtin_amdgcn_mfma_f32_32x32x16_bf16(a, b, acc[ni], 0, 0, 0);
      }
    }
  };

  const int BUFSZ = C_DIM * 32;
  if (nt > 0) {
    f32x4 v0[4], v1[4], v2[4], v3[4];
    load_tile(0, v0);
    if (nt > 1) load_tile(1, v1);
    if (nt > 2) load_tile(2, v2);
    if (nt > 3) load_tile(3, v3);
    write_tile(lds, v0, 0);
    TILE_BARRIER();
    int cur = 0;
    for (int t = 0; t < nt; t += 4) {
      // step t: compute t, stage t+1 (v1), load t+4 -> v0
      if (t + 1 < nt) write_tile(lds + (unsigned)(cur ^ 1) * BUFSZ, v1, t + 1);
      if (t + 4 < nt) load_tile(t + 4, v0);
      compute_tile(lds + (unsigned)cur * BUFSZ);
      TILE_BARRIER(); cur ^= 1;
      if (t + 1 >= nt) break;
      // step t+1: compute t+1, stage t+2 (v2), load t+5 -> v1
      if (t + 2 < nt) write_tile(lds + (unsigned)(cur ^ 1) * BUFSZ, v2, t + 2);
      if (t + 5 < nt) load_tile(t + 5, v1);
      compute_tile(lds + (unsigned)cur * BUFSZ);
      TILE_BARRIER(); cur ^= 1;
      if (t + 2 >= nt) break;
      // step t+2: compute t+2, stage t+3 (v3), load t+6 -> v2
      if (t + 3 < nt) write_tile(lds + (unsigned)(cur ^ 1) * BUFSZ, v3, t + 3);
      if (t + 6 < nt) load_tile(t + 6, v2);
      compute_tile(lds + (unsigned)cur * BUFSZ);
      TILE_BARRIER(); cur ^= 1;
      if (t + 3 >= nt) break;
      // step t+3: compute t+3, stage t+4 (v0), load t+7 -> v3
      if (t + 4 < nt) write_tile(lds + (unsigned)(cur ^ 1) * BUFSZ, v0, t + 4);
      if (t + 7 < nt) load_tile(t + 7, v3);
      compute_tile(lds + (unsigned)cur * BUFSZ);
      TILE_BARRIER(); cur ^= 1;
    }
  }

  // ---- overflow rows (r >= PAD_R): full-stat contribution only, coalesced ----
  float osum[4] = {0.f, 0.f, 0.f, 0.f}, osq[4] = {0.f, 0.f, 0.f, 0.f};
  const int colo = lc << 2;
  for (int r = PAD_R + half + (p << 1); r < cnt_full; r += 32) {
    int row = ordk[r];
    f32x4 vv = *(const f32x4*)(x + (size_t)row * C_DIM + colo);
    #pragma unroll
    for (int e = 0; e < 4; ++e) { float t = vv[e]; osum[e] += t; osq[e] += t * t; }
  }

  // ---- epilogue: reduce trunc-sum / full-sq / ovf-sum, store partial S ----
  __syncthreads();
  float* red = (float*)lds;
  if (tid < 3 * C_DIM) red[tid] = 0.f;
  __syncthreads();
  #pragma unroll
  for (int e = 0; e < 4; ++e) {
    atomicAdd(&red[colo + e], sum4[e]);
    atomicAdd(&red[C_DIM + colo + e], sq4[e] + osq[e]);
    atomicAdd(&red[2 * C_DIM + colo + e], osum[e]);
  }
  __syncthreads();
  if (tid < C_DIM) {
    sums_part[(half * K_CLS + k) * C_DIM + tid] = red[tid];
    sqs_part [(half * K_CLS + k) * C_DIM + tid] = red[C_DIM + tid];
    ovfs_part[(half * K_CLS + k) * C_DIM + tid] = red[2 * C_DIM + tid];
  }
  // C/D (measured m74/m101): col = lane&31, row = (reg&3) + 8*(reg>>2) + 4*(lane>>5)
  float* sp = spart + (size_t)(half * K_CLS + k) * (C_DIM * C_DIM);
  {
    const int h = lane >> 5, r32 = lane & 31;
    #pragma unroll
    for (int ni = 0; ni < 2; ++ni)
      #pragma unroll
      for (int r = 0; r < 16; ++r) {
        int c = qr * 32 + (r & 3) + 8 * (r >> 2) + 4 * h;
        int d = qc * 64 + ni * 32 + r32;
        sp[c * C_DIM + d] = acc[ni][r];
      }
  }
}

// ---------------- per-class analytic corr, off-diag^2 reduction (4 blocks/class) ----------------
__global__ __launch_bounds__(512) void finalize_kernel(const float* __restrict__ spart,
                                                       const float* __restrict__ sums_part,
                                                       const float* __restrict__ sqs_part,
                                                       const float* __restrict__ ovfs_part,
                                                       const int* __restrict__ counts,
                                                       float* __restrict__ numden) {
  __shared__ float m_l[C_DIM], is_l[C_DIM], st_l[C_DIM];
  __shared__ float wred[8];
  const int k = blockIdx.x >> 2, fs = blockIdx.x & 3;
  const int tid = threadIdx.x;
  const int count = counts[k];
  const float Tf = (float)(count < PAD_R ? count : PAD_R);
  if (tid < C_DIM) {
    float s_tr = 0.f, osum = 0.f, fsq = 0.f;
    #pragma unroll
    for (int j = 0; j < QSPLIT; ++j) {
      s_tr += sums_part[(j * K_CLS + k) * C_DIM + tid];
      osum += ovfs_part[(j * K_CLS + k) * C_DIM + tid];
      fsq  += sqs_part [(j * K_CLS + k) * C_DIM + tid];
    }
    float fsum = s_tr + osum;
    float cf = (float)count;
    float m = fsum / fmaxf(cf, 1.f);
    float var = (fsq - cf * m * m) / fmaxf(cf - 1.f, 1.f);
    m_l[tid] = m;
    is_l[tid] = rsqrtf(var + EPS_F);
    st_l[tid] = s_tr;
  }
  __syncthreads();
  float local = 0.f;
  const int e_lo = fs * (C_DIM * C_DIM / FSPLIT);
  const int e_hi = e_lo + (C_DIM * C_DIM / FSPLIT);
  for (int e4 = e_lo + tid * 4; e4 < e_hi; e4 += 512 * 4) {
    int c = e4 >> 7, d0 = e4 & 127;
    f32x4 sa = (f32x4){0.f, 0.f, 0.f, 0.f};
    #pragma unroll
    for (int j = 0; j < QSPLIT; ++j) {
      f32x4 sj = *(const f32x4*)(spart + (size_t)(j * K_CLS + k) * (C_DIM * C_DIM) + e4);
      #pragma unroll
      for (int e = 0; e < 4; ++e) sa[e] += sj[e];
    }
    #pragma unroll
    for (int e = 0; e < 4; ++e) {
      int d = d0 + e;
      float corr = is_l[c] * is_l[d] *
                   (sa[e] - m_l[c] * st_l[d] - m_l[d] * st_l[c] + Tf * m_l[c] * m_l[d]);
      if (c != d) local += corr * corr;
    }
  }
  for (int off = 32; off > 0; off >>= 1) local += __shfl_down(local, off);
  int lane = tid & 63, wid = tid >> 6;
  if (lane == 0) wred[wid] = local;
  __syncthreads();
  if (tid == 0 && count > 1) {
    float tot = 0.f;
    #pragma unroll
    for (int i = 0; i < 8; ++i) tot += wred[i];
    atomicAdd(&numden[0], tot * (1.f / (float)(C_DIM * (C_DIM - 1))));
    if (fs == 0) atomicAdd(&numden[1], (float)count);
  }
}

__global__ void div_kernel(const float* __restrict__ numden, float* __restrict__ out) {
  if (threadIdx.x == 0 && blockIdx.x == 0)
    out[0] = numden[1] > 0.f ? numden[0] / numden[1] : 0.f;
}

// ---------------- workspace layout (ws_size = 512 MB) ----------------
// [0,256)            numden
// [256, +128K)       hist
// [131328, +512)     counts
// [132096, +2M)      ord (128 * 4096 * 4)
// [2229248, +256K)   sums_part
// [2491392, +256K)   sqs_part
// [2753536, +256K)   ovfs_part
// [3015680, +32M)    spart (2 * 128 * 64KB used)
extern "C" void kernel_launch(void* const* d_in, const int* in_sizes, int n_in,
                              void* d_out, int out_size, void* d_ws, size_t ws_size,
                              hipStream_t stream) {
  (void)in_sizes; (void)n_in; (void)out_size; (void)ws_size;
  const float* x = (const float*)d_in[0];
  const int*   y = (const int*)d_in[1];
  float* out = (float*)d_out;
  char* ws = (char*)d_ws;

  float* numden    = (float*)(ws + 0);
  int*   hist      = (int*)(ws + 256);
  int*   counts    = (int*)(ws + 131328);
  int*   ord       = (int*)(ws + 132096);
  float* sums_part = (float*)(ws + 2229248);
  float* sqs_part  = (float*)(ws + 2491392);
  float* ovfs_part = (float*)(ws + 2753536);
  float* spart     = (float*)(ws + 3015680);

  hist_kernel<<<G_CHUNKS, 256, 0, stream>>>(y, hist, numden);
  scan_kernel<<<K_CLS, 256, 0, stream>>>(hist, counts);
  rank_kernel<<<G_CHUNKS, 256, 0, stream>>>(y, hist, ord);
  gemm_kernel<<<QSPLIT * K_CLS, 512, 0, stream>>>(x, ord, counts, spart, sums_part,
                                                  sqs_part, ovfs_part);
  finalize_kernel<<<FSPLIT * K_CLS, 512, 0, stream>>>(spart, sums_part, sqs_part,
                                                      ovfs_part, counts, numden);
  div_kernel<<<1, 64, 0, stream>>>(numden, out);
}